// Round 17
// baseline (158.010 us; speedup 1.0000x reference)
//
#include <hip/hip_runtime.h>
#include <hip/hip_bf16.h>
#include <math.h>

#define B_N 256
#define F_N 512
#define S_N 100000
#define Q_N 1024
#define EPSF 1e-12f
#define BM 128
#define NBLK ((S_N + BM - 1) / BM)   // 782 row-blocks; grid = 2*NBLK (col halves)

typedef __attribute__((ext_vector_type(8))) short short8v;  // 8 bf16
typedef __attribute__((ext_vector_type(4))) float f32x4;

__device__ __forceinline__ unsigned short f2bf(float x) {  // RNE f32->bf16
  unsigned u = __float_as_uint(x);
  u = u + 0x7FFFu + ((u >> 16) & 1u);
  return (unsigned short)(u >> 16);
}
__device__ __forceinline__ float bf2f(unsigned short h) {
  return __uint_as_float(((unsigned)h) << 16);
}

__device__ __forceinline__ float warpReduceSum(float v) {
  #pragma unroll
  for (int o = 32; o > 0; o >>= 1) v += __shfl_down(v, o);
  return v;
}

__device__ __forceinline__ float blockReduceSum256(float v, float* buf) {
  v = warpReduceSum(v);
  int lane = threadIdx.x & 63, w = threadIdx.x >> 6;
  __syncthreads();
  if (lane == 0) buf[w] = v;
  __syncthreads();
  return buf[0] + buf[1] + buf[2] + buf[3];
}

__device__ __forceinline__ void async_copy16(void* lds, const void* g) {
  __builtin_amdgcn_global_load_lds(
      (const __attribute__((address_space(1))) unsigned int*)g,
      (__attribute__((address_space(3))) unsigned int*)lds, 16, 0, 0);
}

// convert 8 f32 -> hi/lo bf16 fragments (pairs via v_cvt_pk_bf16_f32)
__device__ __forceinline__ void cvt8(const float4 a, const float4 b,
                                     short8v& hi, short8v& lo) {
  union { unsigned u[4]; short8v v; } H, L;
  float xs[8] = {a.x, a.y, a.z, a.w, b.x, b.y, b.z, b.w};
  #pragma unroll
  for (int i = 0; i < 4; ++i) {
    float p = xs[2 * i], q = xs[2 * i + 1];
    union { __hip_bfloat162 b2; unsigned u; } c;
    c.b2 = __float22bfloat162_rn(make_float2(p, q));
    H.u[i] = c.u;
    float rp = p - __uint_as_float(c.u << 16);
    float rq = q - __uint_as_float(c.u & 0xFFFF0000u);
    union { __hip_bfloat162 b2; unsigned u; } d;
    d.b2 = __float22bfloat162_rn(make_float2(rp, rq));
    L.u[i] = d.u;
  }
  hi = H.v; lo = L.v;
}

// -------- K0: L_norm, org (hi/lo bf16 pre-swizzled staged layout), aug,
// keys zero, AND the per-b queue scan (qidx/qcnt) — one block per b, so the
// 4x-redundant scan in k_qdot collapses to 1x here. Identical far-flag
// arithmetic -> bit-identical queue. --------
__global__ __launch_bounds__(256) void k_prep(const float* __restrict__ V,
    const float* __restrict__ L, const float* __restrict__ gps,
    const float* __restrict__ sgps, unsigned short* __restrict__ orgst,
    float* __restrict__ aug, unsigned long long* __restrict__ keys,
    int* __restrict__ qidx, int* __restrict__ qcnt) {
  __shared__ float buf[4];
  __shared__ int wtot[4];
  int b = blockIdx.x, t = threadIdx.x;
  int lane = t & 63, w = t >> 6;
  if (t == 0) keys[b] = 0ull;
  const float2 lv = *(const float2*)&L[b * F_N + t * 2];
  float ss = blockReduceSum256(lv.x * lv.x + lv.y * lv.y, buf);
  float invL = 1.0f / fmaxf(sqrtf(ss), EPSF);
  float lnx = lv.x * invL, lny = lv.y * invL;
  #pragma unroll
  for (int a = 0; a < 3; ++a) {
    const float2 vv = *(const float2*)&V[(a * B_N + b) * F_N + t * 2];
    float yx = vv.x * lnx, yy = vv.y * lny;
    float s2 = blockReduceSum256(yx * yx + yy * yy, buf);
    float inv = 1.0f / fmaxf(sqrtf(s2), EPSF);
    if (a == 0) {
      float ox = yx * inv, oy = yy * inv;
      int f = t * 2;
      int kt = f >> 5, kk = f & 31, sub = kk >> 3, pos = kk & 7;
      unsigned short hx = f2bf(ox), hy = f2bf(oy);
      unsigned short lx = f2bf(ox - bf2f(hx)), ly = f2bf(oy - bf2f(hy));
      int base = kt * 16384 + b * 64;
      ushort2 hv; hv.x = hx; hv.y = hy;
      ushort2 lw; lw.x = lx; lw.y = ly;
      *(ushort2*)&orgst[base + ((sub ^ (b & 7)) << 3) + pos] = hv;
      *(ushort2*)&orgst[base + (((sub | 4) ^ (b & 7)) << 3) + pos] = lw;
    } else {
      float* dst = &aug[((a - 1) * B_N + b) * F_N + t * 2];
      dst[0] = yx * inv;
      dst[1] = yy * inv;
    }
  }

  // ---- per-b queue scan (moved from k_qdot; identical arithmetic) ----
  const float DEG2RAD = 0.017453292519943295f;
  float la = gps[b * 2] * DEG2RAD;
  float lo = gps[b * 2 + 1] * DEG2RAD;
  float ca = cosf(la);
  double xd = 25.0 / (2.0 * 6371.0088);
  float hcut = (float)(sin(xd) * sin(xd));  // dist>25km  <=>  h > hcut

  int cnt = 0;
  for (int base = 0; base < S_N; base += 256) {
    int s = base + t;
    bool far = false;
    if (s < S_N) {
      float lb = sgps[s * 2] * DEG2RAD;
      float ob = sgps[s * 2 + 1] * DEG2RAD;
      float sl = sinf((lb - la) * 0.5f);
      float so = sinf((ob - lo) * 0.5f);
      float h = sl * sl + ca * cosf(lb) * so * so;
      far = h > hcut;
    }
    unsigned long long m = __ballot(far);
    if (lane == 0) wtot[w] = (int)__popcll(m);
    __syncthreads();
    int offs = cnt;
    for (int wi = 0; wi < w; ++wi) offs += wtot[wi];
    if (far) {
      int pos = offs + (int)__popcll(m & ((1ull << lane) - 1ull));
      if (pos < Q_N) qidx[b * Q_N + pos] = s;
    }
    cnt += wtot[0] + wtot[1] + wtot[2] + wtot[3];
    __syncthreads();
    if (cnt >= Q_N) break;
  }
  if (t == 0) qcnt[b] = cnt < Q_N ? cnt : Q_N;
}

// -------- K1: sims GEMM, col-split. Block = 128 s-rows x 128 b-cols.
// 4 waves x (32s x 128b); acc[2][8]=64 AGPR; LDS dbuf 2x16KB -> 4 blocks/CU.
// A: HBM->reg 1-deep prefetch. B: gload_lds dbuf, counted vmcnt(4) + raw
// barrier (stage retired, A kept in flight). 3-pass hi/lo MFMA + setprio.
// Bijective XCD swizzle pairs (rb,half) on one XCD (r16: -4.5 us).
// [BYTE-IDENTICAL to round-16 winner]
__global__ __launch_bounds__(256, 4) void k_sims(const float* __restrict__ support,
    const unsigned short* __restrict__ orgst, unsigned long long* __restrict__ keys) {
  __shared__ __align__(16) unsigned char smem[32768];  // B dbuf 2x16KB

  int t = threadIdx.x;
  int lane = t & 63, w = t >> 6;
  int r15 = lane & 15, ks = lane >> 4;

  // bijective XCD swizzle (m204): nwg = 1564 = 8*195 + 4.
  const int nwg = 2 * NBLK, qq = nwg >> 3, rr8 = nwg & 7;
  int orig = blockIdx.x;
  int xcd = orig & 7, idx = orig >> 3;
  int wgid = (xcd < rr8 ? xcd * (qq + 1) : rr8 * (qq + 1) + (xcd - rr8) * qq) + idx;
  int rb = wgid >> 1, half = wgid & 1;
  int s0 = rb * BM;

  f32x4 acc0[8], acc1[8];
  #pragma unroll
  for (int n = 0; n < 8; ++n) {
    acc0[n] = (f32x4){0.f, 0.f, 0.f, 0.f};
    acc1[n] = (f32x4){0.f, 0.f, 0.f, 0.f};
  }

  int row0 = s0 + w * 32 + r15;       // m=0
  int row1 = row0 + 16;               // m=1
  if (row0 > S_N - 1) row0 = S_N - 1;
  if (row1 > S_N - 1) row1 = S_N - 1;
  const float* ap0 = support + (size_t)row0 * F_N + ks * 8;
  const float* ap1 = support + (size_t)row1 * F_N + ks * 8;

  const unsigned char* bsrc =
      (const unsigned char*)orgst + half * 16384 + t * 16;

  {
    unsigned char* dst = smem + t * 16;
    #pragma unroll
    for (int p = 0; p < 4; ++p) async_copy16(dst + p * 4096, bsrc + p * 4096);
  }
  __builtin_amdgcn_sched_barrier(0);
  float4 a0a = *(const float4*)(ap0);
  float4 a0b = *(const float4*)(ap0 + 4);
  float4 a1a = *(const float4*)(ap1);
  float4 a1b = *(const float4*)(ap1 + 4);
  __builtin_amdgcn_sched_barrier(0);
  asm volatile("s_waitcnt vmcnt(4)" ::: "memory");  // B(0) landed; A(0) flying
  __builtin_amdgcn_s_barrier();
  __builtin_amdgcn_sched_barrier(0);

  const int hioff = (ks ^ (r15 & 7)) << 4;
  const int looff = ((ks | 4) ^ (r15 & 7)) << 4;

  #pragma unroll 1
  for (int kt = 0; kt < 16; ++kt) {
    unsigned char* bbuf = smem + (kt & 1) * 16384;
    short8v ah0, al0, ah1, al1;
    cvt8(a0a, a0b, ah0, al0);
    cvt8(a1a, a1b, ah1, al1);
    if (kt < 15) {
      const unsigned char* src = bsrc + (kt + 1) * 32768;
      unsigned char* dst = smem + ((kt + 1) & 1) * 16384 + t * 16;
      #pragma unroll
      for (int p = 0; p < 4; ++p) async_copy16(dst + p * 4096, src + p * 4096);
      __builtin_amdgcn_sched_barrier(0);  // pin: stage before A-prefetch
      a0a = *(const float4*)(ap0 + (kt + 1) * 32);
      a0b = *(const float4*)(ap0 + (kt + 1) * 32 + 4);
      a1a = *(const float4*)(ap1 + (kt + 1) * 32);
      a1b = *(const float4*)(ap1 + (kt + 1) * 32 + 4);
      __builtin_amdgcn_sched_barrier(0);  // pin: loads issued before compute
    }
    const unsigned char* bp = bbuf + r15 * 128 + hioff;
    const unsigned char* bq = bbuf + r15 * 128 + looff;
    __builtin_amdgcn_s_setprio(1);
    #pragma unroll
    for (int n = 0; n < 8; ++n) {
      short8v bh = *(const short8v*)(bp + n * 2048);
      short8v bl = *(const short8v*)(bq + n * 2048);
      acc0[n] = __builtin_amdgcn_mfma_f32_16x16x32_bf16(ah0, bh, acc0[n], 0, 0, 0);
      acc1[n] = __builtin_amdgcn_mfma_f32_16x16x32_bf16(ah1, bh, acc1[n], 0, 0, 0);
      acc0[n] = __builtin_amdgcn_mfma_f32_16x16x32_bf16(al0, bh, acc0[n], 0, 0, 0);
      acc1[n] = __builtin_amdgcn_mfma_f32_16x16x32_bf16(al1, bh, acc1[n], 0, 0, 0);
      acc0[n] = __builtin_amdgcn_mfma_f32_16x16x32_bf16(ah0, bl, acc0[n], 0, 0, 0);
      acc1[n] = __builtin_amdgcn_mfma_f32_16x16x32_bf16(ah1, bl, acc1[n], 0, 0, 0);
    }
    __builtin_amdgcn_s_setprio(0);
    __builtin_amdgcn_sched_barrier(0);
    if (kt < 15) {
      asm volatile("s_waitcnt vmcnt(4)" ::: "memory");
      __builtin_amdgcn_s_barrier();
    } else {
      __syncthreads();
    }
    __builtin_amdgcn_sched_barrier(0);
  }

  // ---- per-block argmax over this col-half ----
  unsigned long long* wk = (unsigned long long*)smem;  // [4 waves][128 cols]
  #pragma unroll
  for (int n = 0; n < 8; ++n) {
    float bv = -INFINITY;
    int bi = 0x7FFFFFFF;
    #pragma unroll
    for (int r = 0; r < 4; ++r) {
      int sA = s0 + w * 32 + ks * 4 + r;
      float vA = acc0[n][r];
      if (sA < S_N && (vA > bv || (vA == bv && sA < bi))) { bv = vA; bi = sA; }
      int sB = sA + 16;
      float vB = acc1[n][r];
      if (sB < S_N && (vB > bv || (vB == bv && sB < bi))) { bv = vB; bi = sB; }
    }
    #pragma unroll
    for (int mask = 16; mask <= 32; mask <<= 1) {
      float ov = __shfl_xor(bv, mask);
      int oi = __shfl_xor(bi, mask);
      if (ov > bv || (ov == bv && oi < bi)) { bv = ov; bi = oi; }
    }
    if (lane < 16) {
      unsigned u = __float_as_uint(bv);
      u = (u & 0x80000000u) ? ~u : (u | 0x80000000u);
      wk[w * 128 + n * 16 + lane] =
          ((unsigned long long)u << 32) |
          (unsigned long long)(0xFFFFFFFFu - (unsigned)bi);
    }
  }
  __syncthreads();
  if (t < 128) {
    unsigned long long k0 = wk[t], k1 = wk[128 + t];
    unsigned long long k2 = wk[256 + t], k3 = wk[384 + t];
    unsigned long long m01 = k0 > k1 ? k0 : k1;
    unsigned long long m23 = k2 > k3 ? k2 : k3;
    atomicMax(&keys[half * 128 + t], m01 > m23 ? m01 : m23);
  }
}

// -------- K2: nn = normalize(support[nn_idx]); batch_den --------
__global__ __launch_bounds__(256) void k_nn(const float* __restrict__ support,
    const unsigned long long* __restrict__ keys, const float* __restrict__ aug,
    float* __restrict__ nn, float* __restrict__ bden) {
  __shared__ float buf[4];
  int b = blockIdx.x, t = threadIdx.x;
  int idx = (int)(0xFFFFFFFFu - (unsigned)(keys[b] & 0xFFFFFFFFull));
  const float2 rv = *(const float2*)&support[(size_t)idx * F_N + t * 2];
  float ss = blockReduceSum256(rv.x * rv.x + rv.y * rv.y, buf);
  float inv = 1.0f / fmaxf(sqrtf(ss), EPSF);
  float nx = rv.x * inv, ny = rv.y * inv;
  nn[b * F_N + t * 2] = nx;
  nn[b * F_N + t * 2 + 1] = ny;
  const float2 a0 = *(const float2*)&aug[(0 * B_N + b) * F_N + t * 2];
  const float2 a1 = *(const float2*)&aug[(1 * B_N + b) * F_N + t * 2];
  float d0 = blockReduceSum256(a0.x * nx + a0.y * ny, buf);
  float d1 = blockReduceSum256(a1.x * nx + a1.y * ny, buf);
  if (t == 0) bden[b] = expf(d0 * 10.0f) + expf(d1 * 10.0f);
}

// -------- K3: queue dots, 4 blocks per b (chunk c of 256 q each).
// Scan removed — reads precomputed qidx/qcnt from k_prep. --------
__global__ __launch_bounds__(256) void k_qdot(const float* __restrict__ support,
    const int* __restrict__ qidx, const int* __restrict__ qcnt,
    const float* __restrict__ nn, double* __restrict__ qpart) {
  __shared__ float nns[F_N];
  __shared__ double wacc[4];
  int b = blockIdx.x >> 2, c = blockIdx.x & 3;
  int t = threadIdx.x;
  int lane = t & 63, w = t >> 6;

  *(float2*)&nns[t * 2] = *(const float2*)&nn[b * F_N + t * 2];
  int nvalid = qcnt[b];
  __syncthreads();

  int qlo = c * 256;
  double acc = 0.0;
  for (int j = 0; j < 64; ++j) {
    int q = qlo + w * 64 + j;
    if (q >= nvalid) break;
    int row = qidx[b * Q_N + q];
    const float4* rp = (const float4*)&support[(size_t)row * F_N + lane * 8];
    float4 r0 = rp[0], r1 = rp[1];
    const float4 n0 = *(const float4*)&nns[lane * 8];
    const float4 n1 = *(const float4*)&nns[lane * 8 + 4];
    float dot = r0.x * n0.x + r0.y * n0.y + r0.z * n0.z + r0.w * n0.w +
                r1.x * n1.x + r1.y * n1.y + r1.z * n1.z + r1.w * n1.w;
    float ssq = r0.x * r0.x + r0.y * r0.y + r0.z * r0.z + r0.w * r0.w +
                r1.x * r1.x + r1.y * r1.y + r1.z * r1.z + r1.w * r1.w;
    #pragma unroll
    for (int o = 32; o > 0; o >>= 1) {
      dot += __shfl_xor(dot, o);
      ssq += __shfl_xor(ssq, o);
    }
    float val = dot / fmaxf(sqrtf(ssq), EPSF);
    acc += (double)expf(val * 10.0f);
  }
  if (lane == 0) wacc[w] = acc;
  __syncthreads();
  if (t == 0) {
    int got = nvalid - qlo;                 // valid q in this chunk
    if (got < 0) got = 0; if (got > 256) got = 256;
    int inval = 256 - got;                  // zero rows contribute exp(0)=1
    qpart[blockIdx.x] = wacc[0] + wacc[1] + wacc[2] + wacc[3] + (double)inval;
  }
}

// -------- K4: fold qpart + bden -> loss --------
__global__ __launch_bounds__(256) void k_final(const double* __restrict__ qpart,
    const float* __restrict__ bden, float* __restrict__ out) {
  __shared__ double buf[4];
  int t = threadIdx.x;
  double qd = qpart[t * 4] + qpart[t * 4 + 1] + qpart[t * 4 + 2] + qpart[t * 4 + 3];
  double bd = (double)bden[t];
  double v = -bd / (bd + qd);
  #pragma unroll
  for (int o = 32; o > 0; o >>= 1) v += __shfl_down(v, o);
  if ((t & 63) == 0) buf[t >> 6] = v;
  __syncthreads();
  if (t == 0) out[0] = (float)((buf[0] + buf[1] + buf[2] + buf[3]) / 256.0);
}

extern "C" void kernel_launch(void* const* d_in, const int* in_sizes, int n_in,
                              void* d_out, int out_size, void* d_ws, size_t ws_size,
                              hipStream_t stream) {
  const float* V = (const float*)d_in[0];
  const float* L = (const float*)d_in[1];
  const float* gps = (const float*)d_in[2];
  const float* support = (const float*)d_in[3];
  const float* sgps = (const float*)d_in[4];
  float* out = (float*)d_out;

  char* ws = (char*)d_ws;
  unsigned long long* keys = (unsigned long long*)ws;      // 2 KB @0
  float* bden = (float*)(ws + 2048);                       // 1 KB
  double* qpart = (double*)(ws + 4096);                    // 8 KB
  int* qcnt = (int*)(ws + 12288 - 1024 + 1024);            // reuse: see below
  unsigned short* orgst = (unsigned short*)(ws + 16384);   // 512 KB
  float* aug = (float*)(ws + 16384 + 524288);              // 1 MB
  float* nn = (float*)(ws + 16384 + 524288 + 1048576);     // 512 KB
  int* qidx = (int*)(ws + 16384 + 524288 + 1048576 + 524288);  // 1 MB
  qcnt = (int*)(ws + 12288);                               // 1 KB @12288

  k_prep<<<256, 256, 0, stream>>>(V, L, gps, sgps, orgst, aug, keys, qidx, qcnt);
  k_sims<<<2 * NBLK, 256, 0, stream>>>(support, orgst, keys);
  k_nn<<<256, 256, 0, stream>>>(support, keys, aug, nn, bden);
  k_qdot<<<1024, 256, 0, stream>>>(support, qidx, qcnt, nn, qpart);
  k_final<<<1, 256, 0, stream>>>(qpart, bden, out);
}

// Round 18
// 154.106 us; speedup vs baseline: 1.0253x; 1.0253x over previous
//
#include <hip/hip_runtime.h>
#include <hip/hip_bf16.h>
#include <math.h>

#define B_N 256
#define F_N 512
#define S_N 100000
#define Q_N 1024
#define EPSF 1e-12f
#define BM 128
#define NBLK ((S_N + BM - 1) / BM)   // 782 row-blocks; grid = 2*NBLK (col halves)

typedef __attribute__((ext_vector_type(8))) short short8v;  // 8 bf16
typedef __attribute__((ext_vector_type(4))) float f32x4;

__device__ __forceinline__ unsigned short f2bf(float x) {  // RNE f32->bf16
  unsigned u = __float_as_uint(x);
  u = u + 0x7FFFu + ((u >> 16) & 1u);
  return (unsigned short)(u >> 16);
}
__device__ __forceinline__ float bf2f(unsigned short h) {
  return __uint_as_float(((unsigned)h) << 16);
}

__device__ __forceinline__ float warpReduceSum(float v) {
  #pragma unroll
  for (int o = 32; o > 0; o >>= 1) v += __shfl_down(v, o);
  return v;
}

__device__ __forceinline__ float blockReduceSum256(float v, float* buf) {
  v = warpReduceSum(v);
  int lane = threadIdx.x & 63, w = threadIdx.x >> 6;
  __syncthreads();
  if (lane == 0) buf[w] = v;
  __syncthreads();
  return buf[0] + buf[1] + buf[2] + buf[3];
}

__device__ __forceinline__ void async_copy16(void* lds, const void* g) {
  __builtin_amdgcn_global_load_lds(
      (const __attribute__((address_space(1))) unsigned int*)g,
      (__attribute__((address_space(3))) unsigned int*)lds, 16, 0, 0);
}

// convert 8 f32 -> hi/lo bf16 fragments (pairs via v_cvt_pk_bf16_f32)
__device__ __forceinline__ void cvt8(const float4 a, const float4 b,
                                     short8v& hi, short8v& lo) {
  union { unsigned u[4]; short8v v; } H, L;
  float xs[8] = {a.x, a.y, a.z, a.w, b.x, b.y, b.z, b.w};
  #pragma unroll
  for (int i = 0; i < 4; ++i) {
    float p = xs[2 * i], q = xs[2 * i + 1];
    union { __hip_bfloat162 b2; unsigned u; } c;
    c.b2 = __float22bfloat162_rn(make_float2(p, q));
    H.u[i] = c.u;
    float rp = p - __uint_as_float(c.u << 16);
    float rq = q - __uint_as_float(c.u & 0xFFFF0000u);
    union { __hip_bfloat162 b2; unsigned u; } d;
    d.b2 = __float22bfloat162_rn(make_float2(rp, rq));
    L.u[i] = d.u;
  }
  hi = H.v; lo = L.v;
}

// -------- K0: L_norm, org (hi/lo bf16 pre-swizzled staged layout), aug --------
// orgst[kt][b][slot^(b&7)][8]  (slots 0-3 = hi k-subslots, 4-7 = lo)
// also zeroes keys[] (replaces a separate memset dispatch)
__global__ __launch_bounds__(256) void k_prep(const float* __restrict__ V,
    const float* __restrict__ L, unsigned short* __restrict__ orgst,
    float* __restrict__ aug, unsigned long long* __restrict__ keys) {
  __shared__ float buf[4];
  int b = blockIdx.x, t = threadIdx.x;
  if (t == 0) keys[b] = 0ull;
  const float2 lv = *(const float2*)&L[b * F_N + t * 2];
  float ss = blockReduceSum256(lv.x * lv.x + lv.y * lv.y, buf);
  float invL = 1.0f / fmaxf(sqrtf(ss), EPSF);
  float lnx = lv.x * invL, lny = lv.y * invL;
  #pragma unroll
  for (int a = 0; a < 3; ++a) {
    const float2 vv = *(const float2*)&V[(a * B_N + b) * F_N + t * 2];
    float yx = vv.x * lnx, yy = vv.y * lny;
    float s2 = blockReduceSum256(yx * yx + yy * yy, buf);
    float inv = 1.0f / fmaxf(sqrtf(s2), EPSF);
    if (a == 0) {
      float ox = yx * inv, oy = yy * inv;
      int f = t * 2;
      int kt = f >> 5, kk = f & 31, sub = kk >> 3, pos = kk & 7;
      unsigned short hx = f2bf(ox), hy = f2bf(oy);
      unsigned short lx = f2bf(ox - bf2f(hx)), ly = f2bf(oy - bf2f(hy));
      int base = kt * 16384 + b * 64;
      ushort2 hv; hv.x = hx; hv.y = hy;
      ushort2 lw; lw.x = lx; lw.y = ly;
      *(ushort2*)&orgst[base + ((sub ^ (b & 7)) << 3) + pos] = hv;
      *(ushort2*)&orgst[base + (((sub | 4) ^ (b & 7)) << 3) + pos] = lw;
    } else {
      float* dst = &aug[((a - 1) * B_N + b) * F_N + t * 2];
      dst[0] = yx * inv;
      dst[1] = yy * inv;
    }
  }
}

// -------- K1: sims GEMM, col-split. Block = 128 s-rows x 128 b-cols.
// 4 waves x (32s x 128b); acc[2][8]=64 AGPR; LDS dbuf 2x16KB -> 4 blocks/CU.
// A: HBM->reg 1-deep prefetch. B: gload_lds dbuf, counted vmcnt(4) + raw
// barrier (stage retired, A kept in flight). 3-pass hi/lo MFMA + setprio.
// Bijective XCD swizzle pairs (rb,half) on one XCD.
// [Measured session optimum: 154.6 us total (round 16)]
__global__ __launch_bounds__(256, 4) void k_sims(const float* __restrict__ support,
    const unsigned short* __restrict__ orgst, unsigned long long* __restrict__ keys) {
  __shared__ __align__(16) unsigned char smem[32768];  // B dbuf 2x16KB

  int t = threadIdx.x;
  int lane = t & 63, w = t >> 6;
  int r15 = lane & 15, ks = lane >> 4;

  // bijective XCD swizzle (m204): nwg = 1564 = 8*195 + 4.
  // wgid = contiguous chunk per XCD; (rb,half) = (wgid>>1, wgid&1) so the
  // two col-halves of one row-block are adjacent -> same XCD chunk.
  const int nwg = 2 * NBLK, qq = nwg >> 3, rr8 = nwg & 7;
  int orig = blockIdx.x;
  int xcd = orig & 7, idx = orig >> 3;
  int wgid = (xcd < rr8 ? xcd * (qq + 1) : rr8 * (qq + 1) + (xcd - rr8) * qq) + idx;
  int rb = wgid >> 1, half = wgid & 1;
  int s0 = rb * BM;

  f32x4 acc0[8], acc1[8];
  #pragma unroll
  for (int n = 0; n < 8; ++n) {
    acc0[n] = (f32x4){0.f, 0.f, 0.f, 0.f};
    acc1[n] = (f32x4){0.f, 0.f, 0.f, 0.f};
  }

  int row0 = s0 + w * 32 + r15;       // m=0
  int row1 = row0 + 16;               // m=1
  if (row0 > S_N - 1) row0 = S_N - 1;
  if (row1 > S_N - 1) row1 = S_N - 1;
  const float* ap0 = support + (size_t)row0 * F_N + ks * 8;
  const float* ap1 = support + (size_t)row1 * F_N + ks * 8;

  // this block's col-half within each 32KB kt slab of orgst
  const unsigned char* bsrc =
      (const unsigned char*)orgst + half * 16384 + t * 16;

  // prologue: stage B(0) (4 gload_lds, oldest), A(0) (4 dwordx4, youngest)
  {
    unsigned char* dst = smem + t * 16;
    #pragma unroll
    for (int p = 0; p < 4; ++p) async_copy16(dst + p * 4096, bsrc + p * 4096);
  }
  __builtin_amdgcn_sched_barrier(0);
  float4 a0a = *(const float4*)(ap0);
  float4 a0b = *(const float4*)(ap0 + 4);
  float4 a1a = *(const float4*)(ap1);
  float4 a1b = *(const float4*)(ap1 + 4);
  __builtin_amdgcn_sched_barrier(0);
  asm volatile("s_waitcnt vmcnt(4)" ::: "memory");  // B(0) landed; A(0) flying
  __builtin_amdgcn_s_barrier();
  __builtin_amdgcn_sched_barrier(0);

  const int hioff = (ks ^ (r15 & 7)) << 4;
  const int looff = ((ks | 4) ^ (r15 & 7)) << 4;

  #pragma unroll 1
  for (int kt = 0; kt < 16; ++kt) {
    unsigned char* bbuf = smem + (kt & 1) * 16384;
    // convert current A regs (implicit wait covers only the 4 A loads)
    short8v ah0, al0, ah1, al1;
    cvt8(a0a, a0b, ah0, al0);
    cvt8(a1a, a1b, ah1, al1);
    if (kt < 15) {
      // stage next B half-tile (4 gload_lds, oldest outstanding)
      const unsigned char* src = bsrc + (kt + 1) * 32768;
      unsigned char* dst = smem + ((kt + 1) & 1) * 16384 + t * 16;
      #pragma unroll
      for (int p = 0; p < 4; ++p) async_copy16(dst + p * 4096, src + p * 4096);
      __builtin_amdgcn_sched_barrier(0);  // pin: stage before A-prefetch
      a0a = *(const float4*)(ap0 + (kt + 1) * 32);
      a0b = *(const float4*)(ap0 + (kt + 1) * 32 + 4);
      a1a = *(const float4*)(ap1 + (kt + 1) * 32);
      a1b = *(const float4*)(ap1 + (kt + 1) * 32 + 4);
      __builtin_amdgcn_sched_barrier(0);  // pin: loads issued before compute
    }
    // compute: 8 n-tiles x (2 m x 3 passes), wave favored on the CU scheduler
    const unsigned char* bp = bbuf + r15 * 128 + hioff;
    const unsigned char* bq = bbuf + r15 * 128 + looff;
    __builtin_amdgcn_s_setprio(1);
    #pragma unroll
    for (int n = 0; n < 8; ++n) {
      short8v bh = *(const short8v*)(bp + n * 2048);
      short8v bl = *(const short8v*)(bq + n * 2048);
      acc0[n] = __builtin_amdgcn_mfma_f32_16x16x32_bf16(ah0, bh, acc0[n], 0, 0, 0);
      acc1[n] = __builtin_amdgcn_mfma_f32_16x16x32_bf16(ah1, bh, acc1[n], 0, 0, 0);
      acc0[n] = __builtin_amdgcn_mfma_f32_16x16x32_bf16(al0, bh, acc0[n], 0, 0, 0);
      acc1[n] = __builtin_amdgcn_mfma_f32_16x16x32_bf16(al1, bh, acc1[n], 0, 0, 0);
      acc0[n] = __builtin_amdgcn_mfma_f32_16x16x32_bf16(ah0, bl, acc0[n], 0, 0, 0);
      acc1[n] = __builtin_amdgcn_mfma_f32_16x16x32_bf16(ah1, bl, acc1[n], 0, 0, 0);
    }
    __builtin_amdgcn_s_setprio(0);
    __builtin_amdgcn_sched_barrier(0);
    if (kt < 15) {
      // retire the 4 B-stage ops; keep the 4 A loads in flight
      asm volatile("s_waitcnt vmcnt(4)" ::: "memory");
      __builtin_amdgcn_s_barrier();
    } else {
      __syncthreads();
    }
    __builtin_amdgcn_sched_barrier(0);
  }

  // ---- per-block argmax over this col-half: C layout col=lane&15,
  // row=(lane>>4)*4+reg ----
  unsigned long long* wk = (unsigned long long*)smem;  // [4 waves][128 cols]
  #pragma unroll
  for (int n = 0; n < 8; ++n) {
    float bv = -INFINITY;
    int bi = 0x7FFFFFFF;
    #pragma unroll
    for (int r = 0; r < 4; ++r) {
      int sA = s0 + w * 32 + ks * 4 + r;
      float vA = acc0[n][r];
      if (sA < S_N && (vA > bv || (vA == bv && sA < bi))) { bv = vA; bi = sA; }
      int sB = sA + 16;
      float vB = acc1[n][r];
      if (sB < S_N && (vB > bv || (vB == bv && sB < bi))) { bv = vB; bi = sB; }
    }
    #pragma unroll
    for (int mask = 16; mask <= 32; mask <<= 1) {
      float ov = __shfl_xor(bv, mask);
      int oi = __shfl_xor(bi, mask);
      if (ov > bv || (ov == bv && oi < bi)) { bv = ov; bi = oi; }
    }
    if (lane < 16) {
      unsigned u = __float_as_uint(bv);
      u = (u & 0x80000000u) ? ~u : (u | 0x80000000u);
      wk[w * 128 + n * 16 + lane] =
          ((unsigned long long)u << 32) |
          (unsigned long long)(0xFFFFFFFFu - (unsigned)bi);
    }
  }
  __syncthreads();
  if (t < 128) {
    unsigned long long k0 = wk[t], k1 = wk[128 + t];
    unsigned long long k2 = wk[256 + t], k3 = wk[384 + t];
    unsigned long long m01 = k0 > k1 ? k0 : k1;
    unsigned long long m23 = k2 > k3 ? k2 : k3;
    atomicMax(&keys[half * 128 + t], m01 > m23 ? m01 : m23);
  }
}

// -------- K2: nn = normalize(support[nn_idx]); batch_den --------
__global__ __launch_bounds__(256) void k_nn(const float* __restrict__ support,
    const unsigned long long* __restrict__ keys, const float* __restrict__ aug,
    float* __restrict__ nn, float* __restrict__ bden) {
  __shared__ float buf[4];
  int b = blockIdx.x, t = threadIdx.x;
  int idx = (int)(0xFFFFFFFFu - (unsigned)(keys[b] & 0xFFFFFFFFull));
  const float2 rv = *(const float2*)&support[(size_t)idx * F_N + t * 2];
  float ss = blockReduceSum256(rv.x * rv.x + rv.y * rv.y, buf);
  float inv = 1.0f / fmaxf(sqrtf(ss), EPSF);
  float nx = rv.x * inv, ny = rv.y * inv;
  nn[b * F_N + t * 2] = nx;
  nn[b * F_N + t * 2 + 1] = ny;
  const float2 a0 = *(const float2*)&aug[(0 * B_N + b) * F_N + t * 2];
  const float2 a1 = *(const float2*)&aug[(1 * B_N + b) * F_N + t * 2];
  float d0 = blockReduceSum256(a0.x * nx + a0.y * ny, buf);
  float d1 = blockReduceSum256(a1.x * nx + a1.y * ny, buf);
  if (t == 0) bden[b] = expf(d0 * 10.0f) + expf(d1 * 10.0f);
}

// -------- K3: queue dots, 4 blocks per b (chunk c of 256 q each) --------
__global__ __launch_bounds__(256) void k_qdot(const float* __restrict__ support,
    const float* __restrict__ gps, const float* __restrict__ sgps,
    const float* __restrict__ nn, double* __restrict__ qpart) {
  __shared__ float nns[F_N];
  __shared__ int qi[256];
  __shared__ int wtot[4];
  __shared__ double wacc[4];
  int b = blockIdx.x >> 2, c = blockIdx.x & 3;
  int t = threadIdx.x;
  int lane = t & 63, w = t >> 6;

  *(float2*)&nns[t * 2] = *(const float2*)&nn[b * F_N + t * 2];

  const float DEG2RAD = 0.017453292519943295f;
  float la = gps[b * 2] * DEG2RAD;
  float lo = gps[b * 2 + 1] * DEG2RAD;
  float ca = cosf(la);
  double xd = 25.0 / (2.0 * 6371.0088);
  float hcut = (float)(sin(xd) * sin(xd));  // dist>25km  <=>  h > hcut

  int cnt = 0;
  int qlo = c * 256;
  for (int base = 0; base < S_N; base += 256) {
    int s = base + t;
    bool far = false;
    if (s < S_N) {
      float lb = sgps[s * 2] * DEG2RAD;
      float ob = sgps[s * 2 + 1] * DEG2RAD;
      float sl = sinf((lb - la) * 0.5f);
      float so = sinf((ob - lo) * 0.5f);
      float h = sl * sl + ca * cosf(lb) * so * so;
      far = h > hcut;
    }
    unsigned long long m = __ballot(far);
    if (lane == 0) wtot[w] = (int)__popcll(m);
    __syncthreads();
    int offs = cnt;
    for (int wi = 0; wi < w; ++wi) offs += wtot[wi];
    if (far) {
      int pos = offs + (int)__popcll(m & ((1ull << lane) - 1ull));
      int rel = pos - qlo;
      if (rel >= 0 && rel < 256) qi[rel] = s;
    }
    cnt += wtot[0] + wtot[1] + wtot[2] + wtot[3];
    __syncthreads();
    if (cnt >= Q_N) break;
  }
  int nvalid = cnt < Q_N ? cnt : Q_N;
  __syncthreads();

  double acc = 0.0;
  for (int j = 0; j < 64; ++j) {
    int q = qlo + w * 64 + j;
    if (q >= nvalid) break;
    int row = qi[w * 64 + j];
    const float4* rp = (const float4*)&support[(size_t)row * F_N + lane * 8];
    float4 r0 = rp[0], r1 = rp[1];
    const float4 n0 = *(const float4*)&nns[lane * 8];
    const float4 n1 = *(const float4*)&nns[lane * 8 + 4];
    float dot = r0.x * n0.x + r0.y * n0.y + r0.z * n0.z + r0.w * n0.w +
                r1.x * n1.x + r1.y * n1.y + r1.z * n1.z + r1.w * n1.w;
    float ssq = r0.x * r0.x + r0.y * r0.y + r0.z * r0.z + r0.w * r0.w +
                r1.x * r1.x + r1.y * r1.y + r1.z * r1.z + r1.w * r1.w;
    #pragma unroll
    for (int o = 32; o > 0; o >>= 1) {
      dot += __shfl_xor(dot, o);
      ssq += __shfl_xor(ssq, o);
    }
    float val = dot / fmaxf(sqrtf(ssq), EPSF);
    acc += (double)expf(val * 10.0f);
  }
  if (lane == 0) wacc[w] = acc;
  __syncthreads();
  if (t == 0) {
    int got = nvalid - qlo;                 // valid q in this chunk
    if (got < 0) got = 0; if (got > 256) got = 256;
    int inval = 256 - got;                  // zero rows contribute exp(0)=1
    qpart[blockIdx.x] = wacc[0] + wacc[1] + wacc[2] + wacc[3] + (double)inval;
  }
}

// -------- K4: fold qpart + bden -> loss --------
__global__ __launch_bounds__(256) void k_final(const double* __restrict__ qpart,
    const float* __restrict__ bden, float* __restrict__ out) {
  __shared__ double buf[4];
  int t = threadIdx.x;
  double qd = qpart[t * 4] + qpart[t * 4 + 1] + qpart[t * 4 + 2] + qpart[t * 4 + 3];
  double bd = (double)bden[t];
  double v = -bd / (bd + qd);
  #pragma unroll
  for (int o = 32; o > 0; o >>= 1) v += __shfl_down(v, o);
  if ((t & 63) == 0) buf[t >> 6] = v;
  __syncthreads();
  if (t == 0) out[0] = (float)((buf[0] + buf[1] + buf[2] + buf[3]) / 256.0);
}

extern "C" void kernel_launch(void* const* d_in, const int* in_sizes, int n_in,
                              void* d_out, int out_size, void* d_ws, size_t ws_size,
                              hipStream_t stream) {
  const float* V = (const float*)d_in[0];
  const float* L = (const float*)d_in[1];
  const float* gps = (const float*)d_in[2];
  const float* support = (const float*)d_in[3];
  const float* sgps = (const float*)d_in[4];
  float* out = (float*)d_out;

  char* ws = (char*)d_ws;
  unsigned long long* keys = (unsigned long long*)ws;      // 2 KB @0
  float* bden = (float*)(ws + 2048);                       // 1 KB
  double* qpart = (double*)(ws + 4096);                    // 8 KB
  unsigned short* orgst = (unsigned short*)(ws + 12288);   // 512 KB
  float* aug = (float*)(ws + 12288 + 524288);              // 1 MB
  float* nn = (float*)(ws + 12288 + 524288 + 1048576);     // 512 KB

  k_prep<<<256, 256, 0, stream>>>(V, L, orgst, aug, keys);
  k_sims<<<2 * NBLK, 256, 0, stream>>>(support, orgst, keys);
  k_nn<<<256, 256, 0, stream>>>(support, keys, aug, nn, bden);
  k_qdot<<<1024, 256, 0, stream>>>(support, gps, sgps, nn, qpart);
  k_final<<<1, 256, 0, stream>>>(qpart, bden, out);
}